// Round 1
// 743.943 us; speedup vs baseline: 1.0013x; 1.0013x over previous
//
#include <hip/hip_runtime.h>
#include <math.h>

#define BATCH    16384
#define N_SPARSE 26
#define N_DENSE  13
#define VOCAB    100000
#define EMB      64

// 4 batch rows per 64-lane wave. lane = 16*g + m:
//   g = lane>>4  : which of the 4 batch rows this lane serves
//   m = lane&15  : which quad of embedding dims (dims 4m..4m+3)
// Each emb2 gather: 16 lanes x float4 = 256B = one embedding row, and one
// wave-level global_load_dwordx4 fetches 1KB = 4 rows (one per sub-row g).
// vs previous kernel: 4x fewer VMEM instructions, 4x fewer waves, 4x less
// address math and shuffle traffic for the same gathered bytes.
__global__ __launch_bounds__(256) void fm_mtl_kernel(
    const int*   __restrict__ sparse,    // [B, 26]
    const float* __restrict__ dense,     // [B, 13]
    const float* __restrict__ emb1,      // [26, V, 1]
    const float* __restrict__ emb2,      // [26, V, 64]
    const float* __restrict__ W_dense,   // [13, 1]
    const float* __restrict__ b_dense,   // [1]
    const float* __restrict__ W_finish,  // [1,1]
    const float* __restrict__ b_finish,  // [1]
    const float* __restrict__ W_like,    // [1,1]
    const float* __restrict__ b_like,    // [1]
    float*       __restrict__ out)       // [2*B] : finish ++ like
{
    const int gtid = blockIdx.x * blockDim.x + threadIdx.x;
    const int wave = gtid >> 6;          // wave id; each wave = 4 batch rows
    const int lane = threadIdx.x & 63;
    const int g    = lane >> 4;          // sub-row 0..3
    const int m    = lane & 15;          // dim-quad 0..15
    const int row  = wave * 4 + g;
    if (row >= BATCH) return;

    // Index staging: lane m<13 of group g holds fields m and m+13 of its row.
    int idx_a = 0, idx_b = 0;
    if (m < N_DENSE) {                   // m < 13
        idx_a = sparse[row * N_SPARSE + m];
        idx_b = sparse[row * N_SPARSE + 13 + m];
    }

    // First-order bits issued early so their latency overlaps the gathers:
    // lin_sparse (emb1, 10.4MB table -> L2/L3 resident) + dense linear.
    float first = 0.0f;
    if (m < N_DENSE) {
        first  = emb1[m * VOCAB + idx_a];
        first += emb1[(13 + m) * VOCAB + idx_b];
        first += dense[row * N_DENSE + m] * W_dense[m];
    }

    // FM second order: each lane accumulates dims 4m..4m+3 of its sub-row.
    float4 s = make_float4(0.f, 0.f, 0.f, 0.f);
    float4 q = make_float4(0.f, 0.f, 0.f, 0.f);
    #pragma unroll
    for (int f = 0; f < N_SPARSE; ++f) {
        // Broadcast field f's index for this lane's own sub-row g.
        const int src = (lane & 48) | (f < 13 ? f : f - 13);
        const int idx = __shfl((f < 13) ? idx_a : idx_b, src);
        const float4* p = (const float4*)(emb2 +
                            ((size_t)f * VOCAB + (size_t)idx) * EMB);
        const float4 v = p[m];
        s.x += v.x; s.y += v.y; s.z += v.z; s.w += v.w;
        q.x = fmaf(v.x, v.x, q.x);
        q.y = fmaf(v.y, v.y, q.y);
        q.z = fmaf(v.z, v.z, q.z);
        q.w = fmaf(v.w, v.w, q.w);
    }

    // Per-lane partial: 0.5*(summed^2 - squared) over this lane's 4 dims,
    // plus this lane's first-order contribution.
    float partial = 0.5f * ((s.x * s.x - q.x) + (s.y * s.y - q.y) +
                            (s.z * s.z - q.z) + (s.w * s.w - q.w)) + first;

    // Reduce across the 16 lanes of this sub-row (xor keeps it in-group).
    #pragma unroll
    for (int off = 8; off > 0; off >>= 1)
        partial += __shfl_xor(partial, off);

    if (m == 0) {
        const float logits = partial + b_dense[0];
        const float zf = fmaf(logits, W_finish[0], b_finish[0]);
        const float zl = fmaf(logits, W_like[0],   b_like[0]);
        out[row]         = 1.0f / (1.0f + __expf(-zf));  // finish
        out[BATCH + row] = 1.0f / (1.0f + __expf(-zl));  // like
    }
}

extern "C" void kernel_launch(void* const* d_in, const int* in_sizes, int n_in,
                              void* d_out, int out_size, void* d_ws, size_t ws_size,
                              hipStream_t stream) {
    const int*   sparse   = (const int*)  d_in[0];
    const float* dense    = (const float*)d_in[1];
    const float* emb1     = (const float*)d_in[2];
    const float* emb2     = (const float*)d_in[3];
    const float* W_dense  = (const float*)d_in[4];
    const float* b_dense  = (const float*)d_in[5];
    const float* W_finish = (const float*)d_in[6];
    const float* b_finish = (const float*)d_in[7];
    const float* W_like   = (const float*)d_in[8];
    const float* b_like   = (const float*)d_in[9];
    float* out = (float*)d_out;

    // 4 rows per wave -> 4096 waves -> 1024 blocks of 256 threads.
    const int threads = 256;
    const int blocks  = (BATCH / 4) * 64 / threads;
    fm_mtl_kernel<<<blocks, threads, 0, stream>>>(
        sparse, dense, emb1, emb2,
        W_dense, b_dense, W_finish, b_finish, W_like, b_like, out);
}